// Round 17
// baseline (2435.175 us; speedup 1.0000x reference)
//
#include <hip/hip_runtime.h>
#include <cmath>

// R17: wavefront LSTM, DUAL-STREAM phase overlap.
// R8-R16 post-mortems: T_step ~5200cyc = LDS pipe (~2400: A-frag b128 reads
// are intrinsic-bandwidth-bound at ~12cyc/KB, not conflict-bound) + VALU
// (~1900) CONVOYING through barriers (sum, not max). Fix: two independent
// 16-row streams per block (32 rows, RGN=8, 88 blocks; weights shared):
//   P1: compute_A(s) [LDS-heavy] || update_B(s-1) [VALU-heavy]; barrier;
//   P2: compute_B(s) || update_A(s); barrier.
// Per-stream math bit-identical to R14 (maps validated R8-R16).

namespace {
constexpr int H = 106, G4 = 424, SEQ = 512, BB = 256, KIN0 = 100;
constexpr int GST = 436;            // gates row stride (f32)
constexpr int NTHR = 896;           // 14 waves
constexpr int RGN = 8;              // rowgroups (32 rows: 2 streams x 16)
constexpr int NLAYER = 11;
constexpr int RD = 16;              // ring depth (steps)
constexpr int REL = 56;             // u64 elements per ring row
constexpr int KMAC = 4;             // macro size (steps)
constexpr size_t CNT_STRIDE = 16;
constexpr size_t RING_OFF_B = 65536;
constexpr size_t RING_PER_L = (size_t)RD * BB * REL;   // u64 elements

using f16x8 = __attribute__((ext_vector_type(8))) _Float16;
using f32x4 = __attribute__((ext_vector_type(4))) float;
typedef unsigned long long u64;

__device__ __forceinline__ u64 ald(const u64* p) {
    return __hip_atomic_load(p, __ATOMIC_RELAXED, __HIP_MEMORY_SCOPE_AGENT);
}
__device__ __forceinline__ void ast(u64* p, u64 v) {
    __hip_atomic_store(p, v, __ATOMIC_RELAXED, __HIP_MEMORY_SCOPE_AGENT);
}
__device__ __forceinline__ unsigned aldu(const unsigned* p) {
    return __hip_atomic_load(p, __ATOMIC_RELAXED, __HIP_MEMORY_SCOPE_AGENT);
}
__device__ __forceinline__ void astu(unsigned* p, unsigned v) {
    __hip_atomic_store(p, v, __ATOMIC_RELAXED, __HIP_MEMORY_SCOPE_AGENT);
}
__device__ __forceinline__ void spinc(const unsigned* p, unsigned tgt) {
    while (aldu(p) < tgt) __builtin_amdgcn_s_sleep(8);
}
__device__ __forceinline__ float fast_tanh(float x) {
    float t = __expf(2.0f * x);
    return 1.0f - 2.0f / (t + 1.0f);
}
__device__ __forceinline__ float act_gate(float g, bool istanh) {
    float s = istanh ? 2.0f * g : g;
    float r = 1.0f / (1.0f + __expf(-s));
    return istanh ? 2.0f * r - 1.0f : r;
}
__device__ __forceinline__ unsigned packh2(float a, float b) {
    unsigned lo = (unsigned)__builtin_bit_cast(unsigned short, (_Float16)a);
    unsigned hi = (unsigned)__builtin_bit_cast(unsigned short, (_Float16)b);
    return (hi << 16) | lo;
}

__global__ __launch_bounds__(NTHR)
__attribute__((amdgpu_waves_per_eu(4, 4)))
void lstm_wave(const float* __restrict__ noise,   // (512,256,100) f32
               float* __restrict__ yout,          // (512,256,106) f32
               unsigned* cnt, u64* ring,
               const float* __restrict__ W_ih0, const float* __restrict__ W_hh0,
               const float* __restrict__ b_ih0, const float* __restrict__ b_hh0,
               const float* __restrict__ W_ih,  const float* __restrict__ W_hh,
               const float* __restrict__ b_ih,  const float* __restrict__ b_hh)
{
    const int l = blockIdx.x / RGN;
    const int rg = blockIdx.x % RGN;
    const bool LAST = (l == NLAYER - 1);
    const int K_IN = (l == 0) ? KIN0 : H;

    const float* Wih = (l == 0) ? W_ih0 : W_ih + (size_t)(l - 1) * G4 * H;
    const float* Whh = (l == 0) ? W_hh0 : W_hh + (size_t)(l - 1) * G4 * H;
    const float* pbi = (l == 0) ? b_ih0 : b_ih + (size_t)(l - 1) * G4;
    const float* pbh = (l == 0) ? b_hh0 : b_hh + (size_t)(l - 1) * G4;

    unsigned* cons_my = cnt + (size_t)(l * RGN + rg) * CNT_STRIDE;
    unsigned* cons_in = cnt + (size_t)((l - 1) * RGN + rg) * CNT_STRIDE;
    u64* ring_in  = ring + (size_t)(l - 1) * RING_PER_L;
    u64* ring_out = ring + (size_t)l * RING_PER_L;

    __shared__ __align__(16) _Float16 sx[2][KMAC][16 * 136];  // 34.8 KB
    __shared__ __align__(16) _Float16 sh[2][16 * 136];        //  8.7 KB
    __shared__ float gl[2][16 * GST];                         // 55.8 KB

    const int tid = threadIdx.x;
    const int w = tid >> 6, lane = tid & 63;
    const int l16 = lane & 15, kg = lane >> 4;
    const int lm = tid / 56, ld = tid % 56;   // loader map (row, element)
    const int um = tid / 53, up = tid % 53;   // update map (row, H-pair)

    // ---- weights: 2 N-tiles/wave, 8 k-steps (validated R8-R16); SHARED by
    // both streams ----
    f16x8 bf[2][8];
    float bias[2];
    #pragma unroll
    for (int t = 0; t < 2; ++t) {
        const int n = 16 * (2 * w + t) + l16;
        const bool valid = n < G4;
        const float* pwx = Wih + (size_t)(valid ? n : 0) * K_IN;
        const float* pwh = Whh + (size_t)(valid ? n : 0) * H;
        #pragma unroll
        for (int q = 0; q < 8; ++q) {
            f16x8 v;
            #pragma unroll
            for (int e = 0; e < 8; ++e) {
                const int k = 32 * q + 8 * kg + e;
                float f = 0.0f;
                if (valid) {
                    if (k < 128) { if (k < K_IN) f = pwx[k]; }
                    else { const int kh = k - 128; if (kh < H) f = pwh[kh]; }
                }
                v[e] = (_Float16)f;
            }
            bf[t][q] = v;
        }
        bias[t] = valid ? (pbi[n] + pbh[n]) : 0.0f;
    }

    // ---- init: zero sx (both streams, all slots) + sh (both) ----
    for (int i = tid; i < 2 * KMAC * 1088 + 2 * 1088; i += NTHR) {
        if (i < 2 * KMAC * 1088) ((unsigned*)sx)[i] = 0;
        else ((unsigned*)sh)[i - 2 * KMAC * 1088] = 0;
    }
    float cA0 = 0.f, cA1 = 0.f, cB0 = 0.f, cB1 = 0.f;
    __syncthreads();

    // compute stream st, macro slot ss: MFMA x+h -> act -> gl[st]
    auto COMPUTE = [&](int st, int ss) {
        f32x4 acc[2] = {{0, 0, 0, 0}, {0, 0, 0, 0}};
        const _Float16* ax = &sx[st][ss][l16 * 136 + 8 * kg];
        #pragma unroll
        for (int q = 0; q < 4; ++q) {
            const f16x8 a = *(const f16x8*)(ax + 32 * q);
            acc[0] = __builtin_amdgcn_mfma_f32_16x16x32_f16(a, bf[0][q], acc[0], 0, 0, 0);
            acc[1] = __builtin_amdgcn_mfma_f32_16x16x32_f16(a, bf[1][q], acc[1], 0, 0, 0);
        }
        const _Float16* ah = &sh[st][l16 * 136 + 8 * kg];
        #pragma unroll
        for (int q = 4; q < 8; ++q) {
            const f16x8 a = *(const f16x8*)(ah + 32 * (q - 4));
            acc[0] = __builtin_amdgcn_mfma_f32_16x16x32_f16(a, bf[0][q], acc[0], 0, 0, 0);
            acc[1] = __builtin_amdgcn_mfma_f32_16x16x32_f16(a, bf[1][q], acc[1], 0, 0, 0);
        }
        #pragma unroll
        for (int t = 0; t < 2; ++t) {
            const int n = 16 * (2 * w + t) + l16;
            if (n < G4) {
                const bool istanh = (n >= 2 * H) && (n < 3 * H);
                #pragma unroll
                for (int r = 0; r < 4; ++r)
                    gl[st][(4 * kg + r) * GST + n] = act_gate(acc[t][r] + bias[t], istanh);
            }
        }
    };

    // update stream st at global step s: gl[st] -> c,h -> sh[st] + publish
    auto UPDATE = [&](int st, int s, float& c0, float& c1) {
        if (tid < 848) {
            const float* gm = &gl[st][um * GST];
            const float2 vi = *(const float2*)(gm + 2 * up);
            const float2 vf = *(const float2*)(gm + H + 2 * up);
            const float2 vg = *(const float2*)(gm + 2 * H + 2 * up);
            const float2 vo = *(const float2*)(gm + 3 * H + 2 * up);
            c0 = fmaf(vf.x, c0, vi.x * vg.x);
            c1 = fmaf(vf.y, c1, vi.y * vg.y);
            const float h0 = vo.x * fast_tanh(c0);
            const float h1 = vo.y * fast_tanh(c1);
            const unsigned hw = packh2(h0, h1);
            ((unsigned*)&sh[st][0])[um * 68 + up] = hw;
            const int grow = rg * 32 + st * 16 + um;
            if (LAST) {
                *(float2*)(yout + ((size_t)s * BB + grow) * H + 2 * up) =
                    make_float2(h0, h1);
            } else {
                ast(ring_out + ((size_t)(s & (RD - 1)) * BB + grow) * REL + up,
                    ((u64)(unsigned)(s + 1) << 32) | hw);
            }
        } else if (!LAST) {   // pad elements 53..55 = 0, tagged
            const int t2 = tid - 848, mm = t2 / 3, dd = t2 % 3;
            const int grow = rg * 32 + st * 16 + mm;
            ast(ring_out + ((size_t)(s & (RD - 1)) * BB + grow) * REL + 53 + dd,
                (u64)(unsigned)(s + 1) << 32);
        }
    };

    for (int m = 0; m < SEQ / KMAC; ++m) {
        // ---- acquire: x bundles for both streams, steps 4m..4m+3 ----
        unsigned xw[2][KMAC];
        if (l == 0) {
            #pragma unroll
            for (int st = 0; st < 2; ++st)
                #pragma unroll
                for (int ss = 0; ss < KMAC; ++ss) {
                    unsigned r = 0;
                    if (ld < 50) {
                        const int s = KMAC * m + ss;
                        const int grow = rg * 32 + st * 16 + lm;
                        const float2 t = *(const float2*)(noise +
                            ((size_t)s * BB + grow) * KIN0 + 2 * ld);
                        r = packh2(t.x, t.y);
                    }
                    xw[st][ss] = r;
                }
        } else {
            u64 v[2][KMAC];
            #pragma unroll
            for (int st = 0; st < 2; ++st)
                #pragma unroll
                for (int ss = 0; ss < KMAC; ++ss) {   // issue all 8 (MLP)
                    const int s = KMAC * m + ss;
                    const int grow = rg * 32 + st * 16 + lm;
                    v[st][ss] = ald(ring_in + ((size_t)(s & (RD - 1)) * BB + grow) * REL + ld);
                }
            #pragma unroll
            for (int st = 0; st < 2; ++st)
                #pragma unroll
                for (int ss = 0; ss < KMAC; ++ss) {   // verify tags
                    const int s = KMAC * m + ss;
                    const unsigned expt = (unsigned)(s + 1);
                    const int grow = rg * 32 + st * 16 + lm;
                    const u64* pin = ring_in + ((size_t)(s & (RD - 1)) * BB + grow) * REL + ld;
                    u64 vv = v[st][ss];
                    while ((unsigned)(vv >> 32) != expt) { __builtin_amdgcn_s_sleep(2); vv = ald(pin); }
                    xw[st][ss] = (unsigned)vv;
                }
        }
        // backpressure: writes 4m..4m+3 overwrite 4m-16..4m-13 -> cons>=4m-12
        if (tid == 0 && !LAST && m >= 4) spinc(cons_my, (unsigned)(KMAC * m - 12));
        if (l > 0 || ld < 50) {
            #pragma unroll
            for (int st = 0; st < 2; ++st)
                #pragma unroll
                for (int ss = 0; ss < KMAC; ++ss)
                    ((unsigned*)&sx[st][ss][0])[lm * 68 + ld] = xw[st][ss];
        }
        __syncthreads();   // install visible
        if (tid == 0 && l > 0) astu(cons_in, (unsigned)(KMAC * m + KMAC));

        // ---- substeps: P1 = computeA || updateB(s-1); P2 = computeB || updateA(s) ----
        for (int ss = 0; ss < KMAC; ++ss) {
            const int s = KMAC * m + ss;
            COMPUTE(0, ss);
            if (s > 0) UPDATE(1, s - 1, cB0, cB1);
            __syncthreads();   // P1 -> P2
            COMPUTE(1, ss);
            UPDATE(0, s, cA0, cA1);
            __syncthreads();   // P2 -> next P1
        }
    }
    // epilogue: stream B's final update
    UPDATE(1, SEQ - 1, cB0, cB1);
}
}  // namespace

extern "C" void kernel_launch(void* const* d_in, const int* in_sizes, int n_in,
                              void* d_out, int out_size, void* d_ws, size_t ws_size,
                              hipStream_t stream) {
    const float* noise = (const float*)d_in[0];
    const float* W_ih0 = (const float*)d_in[1];
    const float* W_hh0 = (const float*)d_in[2];
    const float* b_ih0 = (const float*)d_in[3];
    const float* b_hh0 = (const float*)d_in[4];
    const float* W_ih  = (const float*)d_in[5];
    const float* W_hh  = (const float*)d_in[6];
    const float* b_ih  = (const float*)d_in[7];
    const float* b_hh  = (const float*)d_in[8];

    // clear counters + rings each call (replay-safe)
    const size_t clear_bytes = RING_OFF_B + (size_t)10 * RING_PER_L * sizeof(u64);
    hipMemsetAsync(d_ws, 0, clear_bytes, stream);

    unsigned* cnt = (unsigned*)d_ws;
    u64* ring = (u64*)((char*)d_ws + RING_OFF_B);

    lstm_wave<<<dim3(NLAYER * RGN), dim3(NTHR), 0, stream>>>(
        noise, (float*)d_out, cnt, ring,
        W_ih0, W_hh0, b_ih0, b_hh0, W_ih, W_hh, b_ih, b_hh);
}

// Round 18
// 1268.852 us; speedup vs baseline: 1.9192x; 1.9192x over previous
//
#include <hip/hip_runtime.h>
#include <cmath>

// R18 = R14 (best: 1287us) + INSTRUCTION DIET (layout-only; math bit-identical).
// Occupancy-corrected counters: VALUBusy 36% reported = 53% per ACTIVE CU ->
// VALU instruction issue is the largest measured consumer. Cuts:
//  - gl layout [row][4*j+gate]: update reads 2 contiguous ds_read_b128
//    (was 4 scattered b64); gate writes at per-thread CONSTANT offsets
//    (j = n%106, g = n/106 precomputed once -> no per-substep decomposition).
//  - all hot-loop addressing hoisted to constants outside the 512-step loop.
// Acquire/publish/backpressure/maps: R14-validated, unchanged.

namespace {
constexpr int H = 106, G4 = 424, SEQ = 512, BB = 256, KIN0 = 100;
constexpr int GST = 436;            // gates row stride (f32), 424 used
constexpr int NTHR = 896;           // 14 waves
constexpr int RGN = 16;             // rowgroups (16 rows each)
constexpr int NLAYER = 11;
constexpr int RD = 16;              // ring depth (steps); 2 macros
constexpr int REL = 56;             // u64 elements per ring row
constexpr int KMAC = 8;             // macro size (steps)
constexpr size_t CNT_STRIDE = 16;   // dwords per counter (64B)
constexpr size_t RING_OFF_B = 65536;
constexpr size_t RING_PER_L = (size_t)RD * BB * REL;   // u64 elements

using f16x8 = __attribute__((ext_vector_type(8))) _Float16;
using f32x4 = __attribute__((ext_vector_type(4))) float;
typedef unsigned long long u64;

__device__ __forceinline__ u64 ald(const u64* p) {
    return __hip_atomic_load(p, __ATOMIC_RELAXED, __HIP_MEMORY_SCOPE_AGENT);
}
__device__ __forceinline__ void ast(u64* p, u64 v) {
    __hip_atomic_store(p, v, __ATOMIC_RELAXED, __HIP_MEMORY_SCOPE_AGENT);
}
__device__ __forceinline__ unsigned aldu(const unsigned* p) {
    return __hip_atomic_load(p, __ATOMIC_RELAXED, __HIP_MEMORY_SCOPE_AGENT);
}
__device__ __forceinline__ void astu(unsigned* p, unsigned v) {
    __hip_atomic_store(p, v, __ATOMIC_RELAXED, __HIP_MEMORY_SCOPE_AGENT);
}
__device__ __forceinline__ void spinc(const unsigned* p, unsigned tgt) {
    while (aldu(p) < tgt) __builtin_amdgcn_s_sleep(8);
}
__device__ __forceinline__ float fast_tanh(float x) {
    float t = __expf(2.0f * x);
    return 1.0f - 2.0f / (t + 1.0f);
}
__device__ __forceinline__ float act_gate(float g, bool istanh) {
    float s = istanh ? 2.0f * g : g;
    float r = 1.0f / (1.0f + __expf(-s));
    return istanh ? 2.0f * r - 1.0f : r;
}
__device__ __forceinline__ unsigned packh2(float a, float b) {
    unsigned lo = (unsigned)__builtin_bit_cast(unsigned short, (_Float16)a);
    unsigned hi = (unsigned)__builtin_bit_cast(unsigned short, (_Float16)b);
    return (hi << 16) | lo;
}

__global__ __launch_bounds__(NTHR)
__attribute__((amdgpu_waves_per_eu(4, 4)))
void lstm_wave(const float* __restrict__ noise,   // (512,256,100) f32
               float* __restrict__ yout,          // (512,256,106) f32
               unsigned* cnt, u64* ring,
               const float* __restrict__ W_ih0, const float* __restrict__ W_hh0,
               const float* __restrict__ b_ih0, const float* __restrict__ b_hh0,
               const float* __restrict__ W_ih,  const float* __restrict__ W_hh,
               const float* __restrict__ b_ih,  const float* __restrict__ b_hh)
{
    const int l = blockIdx.x / RGN;
    const int rg = blockIdx.x % RGN;
    const bool LAST = (l == NLAYER - 1);
    const int K_IN = (l == 0) ? KIN0 : H;

    const float* Wih = (l == 0) ? W_ih0 : W_ih + (size_t)(l - 1) * G4 * H;
    const float* Whh = (l == 0) ? W_hh0 : W_hh + (size_t)(l - 1) * G4 * H;
    const float* pbi = (l == 0) ? b_ih0 : b_ih + (size_t)(l - 1) * G4;
    const float* pbh = (l == 0) ? b_hh0 : b_hh + (size_t)(l - 1) * G4;

    unsigned* cons_my = cnt + (size_t)(l * RGN + rg) * CNT_STRIDE;
    unsigned* cons_in = cnt + (size_t)((l - 1) * RGN + rg) * CNT_STRIDE;
    u64* ring_in  = ring + (size_t)(l - 1) * RING_PER_L;
    u64* ring_out = ring + (size_t)l * RING_PER_L;

    __shared__ __align__(16) _Float16 sx[KMAC][16 * 136];  // 34.8 KB
    __shared__ __align__(16) _Float16 sh[16 * 136];        //  4.4 KB
    __shared__ __align__(16) float gl[16 * GST];           // 27.9 KB, [row][4j+g]

    const int tid = threadIdx.x;
    const int w = tid >> 6, lane = tid & 63;
    const int l16 = lane & 15, kg = lane >> 4;
    const int lm = tid / 56, ld = tid % 56;   // loader map (row, element)
    const int um = tid / 53, up = tid % 53;   // update map (row, H-pair)

    // ---- weights: 2 N-tiles/wave, 8 k-steps (validated R8-R17) ----
    f16x8 bf[2][8];
    float bias[2];
    // hoisted per-thread constants for the gate write (constant across steps)
    int   goff[2][4];     // dword offset into gl for (t, r)
    bool  gvalid[2], gistanh[2];
    #pragma unroll
    for (int t = 0; t < 2; ++t) {
        const int n = 16 * (2 * w + t) + l16;
        const bool valid = n < G4;
        const float* pwx = Wih + (size_t)(valid ? n : 0) * K_IN;
        const float* pwh = Whh + (size_t)(valid ? n : 0) * H;
        #pragma unroll
        for (int q = 0; q < 8; ++q) {
            f16x8 v;
            #pragma unroll
            for (int e = 0; e < 8; ++e) {
                const int k = 32 * q + 8 * kg + e;
                float f = 0.0f;
                if (valid) {
                    if (k < 128) { if (k < K_IN) f = pwx[k]; }
                    else { const int kh = k - 128; if (kh < H) f = pwh[kh]; }
                }
                v[e] = (_Float16)f;
            }
            bf[t][q] = v;
        }
        bias[t] = valid ? (pbi[n] + pbh[n]) : 0.0f;
        const int jt = valid ? (n % H) : 0;
        const int gt = valid ? (n / H) : 0;
        gvalid[t] = valid;
        gistanh[t] = (gt == 2);
        #pragma unroll
        for (int r = 0; r < 4; ++r)
            goff[t][r] = (4 * kg + r) * GST + 4 * jt + gt;
    }

    // ---- init: zero sx (all slots) + sh ----
    for (int i = tid; i < KMAC * 1088 + 1088; i += NTHR) {
        if (i < KMAC * 1088) ((unsigned*)sx)[i] = 0;
        else ((unsigned*)sh)[i - KMAC * 1088] = 0;
    }
    float c0 = 0.0f, c1 = 0.0f;
    __syncthreads();

    // hoisted bases for update/publish
    const float* gread = gl + um * GST + 8 * up;     // 8 f32 = units 2up,2up+1
    unsigned* shw = ((unsigned*)sh) + um * 68 + up;
    float* ybase = yout + ((size_t)rg * 16 + um) * H + 2 * up;
    u64* rout_base = ring_out + ((size_t)rg * 16 + um) * REL + up;

    for (int m = 0; m < SEQ / KMAC; ++m) {
        // ---- acquire: x bundle for steps 8m..8m+7 (R14-validated) ----
        unsigned xw[KMAC] = {0, 0, 0, 0, 0, 0, 0, 0};
        if (l == 0) {
            if (ld < 50) {
                #pragma unroll
                for (int ss = 0; ss < KMAC; ++ss) {
                    const int s = KMAC * m + ss;
                    const float2 t = *(const float2*)(noise +
                        ((size_t)s * BB + rg * 16 + lm) * KIN0 + 2 * ld);
                    xw[ss] = packh2(t.x, t.y);
                }
            }
        } else {
            const u64* pin0 = ring_in +
                ((size_t)((KMAC * m) & (RD - 1)) * BB + rg * 16 + lm) * REL + ld;
            u64 v[KMAC];
            #pragma unroll
            for (int ss = 0; ss < KMAC; ++ss)      // issue all loads (MLP)
                v[ss] = ald(pin0 + (size_t)ss * BB * REL);
            #pragma unroll
            for (int ss = 0; ss < KMAC; ++ss) {    // verify tags
                const unsigned expt = (unsigned)(KMAC * m + ss + 1);
                const u64* pin = pin0 + (size_t)ss * BB * REL;
                u64 vv = v[ss];
                while ((unsigned)(vv >> 32) != expt) { __builtin_amdgcn_s_sleep(2); vv = ald(pin); }
                xw[ss] = (unsigned)vv;
            }
        }
        if (tid == 0 && !LAST && m >= 2) spinc(cons_my, (unsigned)(KMAC * m - 8));
        if (l > 0 || ld < 50) {
            #pragma unroll
            for (int ss = 0; ss < KMAC; ++ss)
                ((unsigned*)sx)[ss * 1088 + lm * 68 + ld] = xw[ss];
        }
        __syncthreads();   // install done; acquire loads drained
        if (tid == 0 && l > 0) astu(cons_in, (unsigned)(KMAC * m + KMAC));

        // ---- 8 substeps ----
        for (int ss = 0; ss < KMAC; ++ss) {
            const int s = KMAC * m + ss;
            // x-part + h-part MFMAs
            f32x4 acc[2] = {{0, 0, 0, 0}, {0, 0, 0, 0}};
            const _Float16* ax = &sx[ss][l16 * 136 + 8 * kg];
            #pragma unroll
            for (int q = 0; q < 4; ++q) {
                const f16x8 a = *(const f16x8*)(ax + 32 * q);
                acc[0] = __builtin_amdgcn_mfma_f32_16x16x32_f16(a, bf[0][q], acc[0], 0, 0, 0);
                acc[1] = __builtin_amdgcn_mfma_f32_16x16x32_f16(a, bf[1][q], acc[1], 0, 0, 0);
            }
            const _Float16* ah = &sh[l16 * 136 + 8 * kg];
            #pragma unroll
            for (int q = 4; q < 8; ++q) {
                const f16x8 a = *(const f16x8*)(ah + 32 * (q - 4));
                acc[0] = __builtin_amdgcn_mfma_f32_16x16x32_f16(a, bf[0][q], acc[0], 0, 0, 0);
                acc[1] = __builtin_amdgcn_mfma_f32_16x16x32_f16(a, bf[1][q], acc[1], 0, 0, 0);
            }
            // activation -> gl at hoisted constant offsets
            #pragma unroll
            for (int t = 0; t < 2; ++t) {
                if (gvalid[t]) {
                    #pragma unroll
                    for (int r = 0; r < 4; ++r)
                        gl[goff[t][r]] = act_gate(acc[t][r] + bias[t], gistanh[t]);
                }
            }
            __syncthreads();   // B1: gates ready; sh reads of this substep done

            // state update + publish: 2 contiguous b128 reads, hoisted bases
            if (tid < 848) {
                const float4 ga = *(const float4*)(gread);       // i,f,g,o of 2up
                const float4 gb = *(const float4*)(gread + 4);   // i,f,g,o of 2up+1
                c0 = fmaf(ga.y, c0, ga.x * ga.z);
                c1 = fmaf(gb.y, c1, gb.x * gb.z);
                const float h0 = ga.w * fast_tanh(c0);
                const float h1 = gb.w * fast_tanh(c1);
                const unsigned hw = packh2(h0, h1);
                *shw = hw;
                if (LAST) {
                    *(float2*)(ybase + (size_t)s * BB * H) = make_float2(h0, h1);
                } else {
                    ast(rout_base + (size_t)(s & (RD - 1)) * BB * REL,
                        ((u64)(unsigned)(s + 1) << 32) | hw);
                }
            } else if (!LAST) {   // pad elements 53..55 = 0, tagged
                const int t2 = tid - 848, mm = t2 / 3, dd = t2 % 3;
                ast(ring_out + ((size_t)(s & (RD - 1)) * BB + rg * 16 + mm) * REL + 53 + dd,
                    (u64)(unsigned)(s + 1) << 32);
            }
            __syncthreads();   // B2: h_s visible for next substep
        }
    }
}
}  // namespace

extern "C" void kernel_launch(void* const* d_in, const int* in_sizes, int n_in,
                              void* d_out, int out_size, void* d_ws, size_t ws_size,
                              hipStream_t stream) {
    const float* noise = (const float*)d_in[0];
    const float* W_ih0 = (const float*)d_in[1];
    const float* W_hh0 = (const float*)d_in[2];
    const float* b_ih0 = (const float*)d_in[3];
    const float* b_hh0 = (const float*)d_in[4];
    const float* W_ih  = (const float*)d_in[5];
    const float* W_hh  = (const float*)d_in[6];
    const float* b_ih  = (const float*)d_in[7];
    const float* b_hh  = (const float*)d_in[8];

    // clear counters + rings each call (replay-safe)
    const size_t clear_bytes = RING_OFF_B + (size_t)10 * RING_PER_L * sizeof(u64);
    hipMemsetAsync(d_ws, 0, clear_bytes, stream);

    unsigned* cnt = (unsigned*)d_ws;
    u64* ring = (u64*)((char*)d_ws + RING_OFF_B);

    lstm_wave<<<dim3(NLAYER * RGN), dim3(NTHR), 0, stream>>>(
        noise, (float*)d_out, cnt, ring,
        W_ih0, W_hh0, b_ih0, b_hh0, W_ih, W_hh, b_ih, b_hh);
}

// Round 19
// 1241.598 us; speedup vs baseline: 1.9613x; 1.0220x over previous
//
#include <hip/hip_runtime.h>
#include <cmath>

// R19 = R18 (best: 1269us) + accx OVERLAP (R11's lever, isolated on this base;
// in R15 it was confounded with the wave-rebalance regression).
// x-part MFMAs (read only sx) move out of the compute phase into the post-B1
// phase alongside the update: LDS x-reads (~670cyc) overlap update VALU
// (~700cyc) instead of convoying. h-chain starts from C=accx. Accumulation
// order unchanged (x then h) -> absmax bit-exact. All else = R18.

namespace {
constexpr int H = 106, G4 = 424, SEQ = 512, BB = 256, KIN0 = 100;
constexpr int GST = 436;            // gates row stride (f32), [row][4j+g]
constexpr int NTHR = 896;           // 14 waves
constexpr int RGN = 16;             // rowgroups (16 rows each)
constexpr int NLAYER = 11;
constexpr int RD = 16;              // ring depth (steps); 2 macros
constexpr int REL = 56;             // u64 elements per ring row
constexpr int KMAC = 8;             // macro size (steps)
constexpr size_t CNT_STRIDE = 16;   // dwords per counter (64B)
constexpr size_t RING_OFF_B = 65536;
constexpr size_t RING_PER_L = (size_t)RD * BB * REL;   // u64 elements

using f16x8 = __attribute__((ext_vector_type(8))) _Float16;
using f32x4 = __attribute__((ext_vector_type(4))) float;
typedef unsigned long long u64;

__device__ __forceinline__ u64 ald(const u64* p) {
    return __hip_atomic_load(p, __ATOMIC_RELAXED, __HIP_MEMORY_SCOPE_AGENT);
}
__device__ __forceinline__ void ast(u64* p, u64 v) {
    __hip_atomic_store(p, v, __ATOMIC_RELAXED, __HIP_MEMORY_SCOPE_AGENT);
}
__device__ __forceinline__ unsigned aldu(const unsigned* p) {
    return __hip_atomic_load(p, __ATOMIC_RELAXED, __HIP_MEMORY_SCOPE_AGENT);
}
__device__ __forceinline__ void astu(unsigned* p, unsigned v) {
    __hip_atomic_store(p, v, __ATOMIC_RELAXED, __HIP_MEMORY_SCOPE_AGENT);
}
__device__ __forceinline__ void spinc(const unsigned* p, unsigned tgt) {
    while (aldu(p) < tgt) __builtin_amdgcn_s_sleep(8);
}
__device__ __forceinline__ float fast_tanh(float x) {
    float t = __expf(2.0f * x);
    return 1.0f - 2.0f / (t + 1.0f);
}
__device__ __forceinline__ float act_gate(float g, bool istanh) {
    float s = istanh ? 2.0f * g : g;
    float r = 1.0f / (1.0f + __expf(-s));
    return istanh ? 2.0f * r - 1.0f : r;
}
__device__ __forceinline__ unsigned packh2(float a, float b) {
    unsigned lo = (unsigned)__builtin_bit_cast(unsigned short, (_Float16)a);
    unsigned hi = (unsigned)__builtin_bit_cast(unsigned short, (_Float16)b);
    return (hi << 16) | lo;
}

__global__ __launch_bounds__(NTHR)
__attribute__((amdgpu_waves_per_eu(4, 4)))
void lstm_wave(const float* __restrict__ noise,   // (512,256,100) f32
               float* __restrict__ yout,          // (512,256,106) f32
               unsigned* cnt, u64* ring,
               const float* __restrict__ W_ih0, const float* __restrict__ W_hh0,
               const float* __restrict__ b_ih0, const float* __restrict__ b_hh0,
               const float* __restrict__ W_ih,  const float* __restrict__ W_hh,
               const float* __restrict__ b_ih,  const float* __restrict__ b_hh)
{
    const int l = blockIdx.x / RGN;
    const int rg = blockIdx.x % RGN;
    const bool LAST = (l == NLAYER - 1);
    const int K_IN = (l == 0) ? KIN0 : H;

    const float* Wih = (l == 0) ? W_ih0 : W_ih + (size_t)(l - 1) * G4 * H;
    const float* Whh = (l == 0) ? W_hh0 : W_hh + (size_t)(l - 1) * G4 * H;
    const float* pbi = (l == 0) ? b_ih0 : b_ih + (size_t)(l - 1) * G4;
    const float* pbh = (l == 0) ? b_hh0 : b_hh + (size_t)(l - 1) * G4;

    unsigned* cons_my = cnt + (size_t)(l * RGN + rg) * CNT_STRIDE;
    unsigned* cons_in = cnt + (size_t)((l - 1) * RGN + rg) * CNT_STRIDE;
    u64* ring_in  = ring + (size_t)(l - 1) * RING_PER_L;
    u64* ring_out = ring + (size_t)l * RING_PER_L;

    __shared__ __align__(16) _Float16 sx[KMAC][16 * 136];  // 34.8 KB
    __shared__ __align__(16) _Float16 sh[16 * 136];        //  4.4 KB
    __shared__ __align__(16) float gl[16 * GST];           // 27.9 KB

    const int tid = threadIdx.x;
    const int w = tid >> 6, lane = tid & 63;
    const int l16 = lane & 15, kg = lane >> 4;
    const int lm = tid / 56, ld = tid % 56;   // loader map (row, element)
    const int um = tid / 53, up = tid % 53;   // update map (row, H-pair)

    // ---- weights + hoisted constants (R18) ----
    f16x8 bf[2][8];
    float bias[2];
    int   goff[2][4];
    bool  gvalid[2], gistanh[2];
    #pragma unroll
    for (int t = 0; t < 2; ++t) {
        const int n = 16 * (2 * w + t) + l16;
        const bool valid = n < G4;
        const float* pwx = Wih + (size_t)(valid ? n : 0) * K_IN;
        const float* pwh = Whh + (size_t)(valid ? n : 0) * H;
        #pragma unroll
        for (int q = 0; q < 8; ++q) {
            f16x8 v;
            #pragma unroll
            for (int e = 0; e < 8; ++e) {
                const int k = 32 * q + 8 * kg + e;
                float f = 0.0f;
                if (valid) {
                    if (k < 128) { if (k < K_IN) f = pwx[k]; }
                    else { const int kh = k - 128; if (kh < H) f = pwh[kh]; }
                }
                v[e] = (_Float16)f;
            }
            bf[t][q] = v;
        }
        bias[t] = valid ? (pbi[n] + pbh[n]) : 0.0f;
        const int jt = valid ? (n % H) : 0;
        const int gt = valid ? (n / H) : 0;
        gvalid[t] = valid;
        gistanh[t] = (gt == 2);
        #pragma unroll
        for (int r = 0; r < 4; ++r)
            goff[t][r] = (4 * kg + r) * GST + 4 * jt + gt;
    }

    // ---- init: zero sx (all slots) + sh ----
    for (int i = tid; i < KMAC * 1088 + 1088; i += NTHR) {
        if (i < KMAC * 1088) ((unsigned*)sx)[i] = 0;
        else ((unsigned*)sh)[i - KMAC * 1088] = 0;
    }
    float c0 = 0.0f, c1 = 0.0f;
    __syncthreads();

    // hoisted bases for update/publish
    const float* gread = gl + um * GST + 8 * up;
    unsigned* shw = ((unsigned*)sh) + um * 68 + up;
    float* ybase = yout + ((size_t)rg * 16 + um) * H + 2 * up;
    u64* rout_base = ring_out + ((size_t)rg * 16 + um) * REL + up;
    const _Float16* ahb = &sh[l16 * 136 + 8 * kg];

    f32x4 accx[2];

    for (int m = 0; m < SEQ / KMAC; ++m) {
        // ---- acquire: x bundle for steps 8m..8m+7 (R14-validated) ----
        unsigned xw[KMAC] = {0, 0, 0, 0, 0, 0, 0, 0};
        if (l == 0) {
            if (ld < 50) {
                #pragma unroll
                for (int ss = 0; ss < KMAC; ++ss) {
                    const int s = KMAC * m + ss;
                    const float2 t = *(const float2*)(noise +
                        ((size_t)s * BB + rg * 16 + lm) * KIN0 + 2 * ld);
                    xw[ss] = packh2(t.x, t.y);
                }
            }
        } else {
            const u64* pin0 = ring_in +
                ((size_t)((KMAC * m) & (RD - 1)) * BB + rg * 16 + lm) * REL + ld;
            u64 v[KMAC];
            #pragma unroll
            for (int ss = 0; ss < KMAC; ++ss)      // issue all loads (MLP)
                v[ss] = ald(pin0 + (size_t)ss * BB * REL);
            #pragma unroll
            for (int ss = 0; ss < KMAC; ++ss) {    // verify tags
                const unsigned expt = (unsigned)(KMAC * m + ss + 1);
                const u64* pin = pin0 + (size_t)ss * BB * REL;
                u64 vv = v[ss];
                while ((unsigned)(vv >> 32) != expt) { __builtin_amdgcn_s_sleep(2); vv = ald(pin); }
                xw[ss] = (unsigned)vv;
            }
        }
        if (tid == 0 && !LAST && m >= 2) spinc(cons_my, (unsigned)(KMAC * m - 8));
        if (l > 0 || ld < 50) {
            #pragma unroll
            for (int ss = 0; ss < KMAC; ++ss)
                ((unsigned*)sx)[ss * 1088 + lm * 68 + ld] = xw[ss];
        }
        __syncthreads();   // install done; acquire loads drained
        if (tid == 0 && l > 0) astu(cons_in, (unsigned)(KMAC * m + KMAC));

        // ---- accx for substep 0 of this macro ----
        accx[0] = f32x4{0, 0, 0, 0};
        accx[1] = f32x4{0, 0, 0, 0};
        {
            const _Float16* ax = &sx[0][l16 * 136 + 8 * kg];
            #pragma unroll
            for (int q = 0; q < 4; ++q) {
                const f16x8 a = *(const f16x8*)(ax + 32 * q);
                accx[0] = __builtin_amdgcn_mfma_f32_16x16x32_f16(a, bf[0][q], accx[0], 0, 0, 0);
                accx[1] = __builtin_amdgcn_mfma_f32_16x16x32_f16(a, bf[1][q], accx[1], 0, 0, 0);
            }
        }

        // ---- 8 substeps; x-MFMAs of ss+1 overlap the update of ss ----
        for (int ss = 0; ss < KMAC; ++ss) {
            const int s = KMAC * m + ss;
            // h-part MFMAs, C init = accx
            f32x4 acc[2] = {accx[0], accx[1]};
            #pragma unroll
            for (int q = 4; q < 8; ++q) {
                const f16x8 a = *(const f16x8*)(ahb + 32 * (q - 4));
                acc[0] = __builtin_amdgcn_mfma_f32_16x16x32_f16(a, bf[0][q], acc[0], 0, 0, 0);
                acc[1] = __builtin_amdgcn_mfma_f32_16x16x32_f16(a, bf[1][q], acc[1], 0, 0, 0);
            }
            // activation -> gl at hoisted constant offsets
            #pragma unroll
            for (int t = 0; t < 2; ++t) {
                if (gvalid[t]) {
                    #pragma unroll
                    for (int r = 0; r < 4; ++r)
                        gl[goff[t][r]] = act_gate(acc[t][r] + bias[t], gistanh[t]);
                }
            }
            __syncthreads();   // B1: gates ready; sh reads of this substep done

            // phase: update+publish (VALU) || accx(ss+1) x-MFMAs (LDS sx reads)
            if (tid < 848) {
                const float4 ga = *(const float4*)(gread);
                const float4 gb = *(const float4*)(gread + 4);
                c0 = fmaf(ga.y, c0, ga.x * ga.z);
                c1 = fmaf(gb.y, c1, gb.x * gb.z);
                const float h0 = ga.w * fast_tanh(c0);
                const float h1 = gb.w * fast_tanh(c1);
                const unsigned hw = packh2(h0, h1);
                *shw = hw;
                if (LAST) {
                    *(float2*)(ybase + (size_t)s * BB * H) = make_float2(h0, h1);
                } else {
                    ast(rout_base + (size_t)(s & (RD - 1)) * BB * REL,
                        ((u64)(unsigned)(s + 1) << 32) | hw);
                }
            } else if (!LAST) {
                const int t2 = tid - 848, mm = t2 / 3, dd = t2 % 3;
                ast(ring_out + ((size_t)(s & (RD - 1)) * BB + rg * 16 + mm) * REL + 53 + dd,
                    (u64)(unsigned)(s + 1) << 32);
            }
            if (ss + 1 < KMAC) {
                accx[0] = f32x4{0, 0, 0, 0};
                accx[1] = f32x4{0, 0, 0, 0};
                const _Float16* ax = &sx[ss + 1][l16 * 136 + 8 * kg];
                #pragma unroll
                for (int q = 0; q < 4; ++q) {
                    const f16x8 a = *(const f16x8*)(ax + 32 * q);
                    accx[0] = __builtin_amdgcn_mfma_f32_16x16x32_f16(a, bf[0][q], accx[0], 0, 0, 0);
                    accx[1] = __builtin_amdgcn_mfma_f32_16x16x32_f16(a, bf[1][q], accx[1], 0, 0, 0);
                }
            }
            __syncthreads();   // B2: h_s visible for next substep
        }
    }
}
}  // namespace

extern "C" void kernel_launch(void* const* d_in, const int* in_sizes, int n_in,
                              void* d_out, int out_size, void* d_ws, size_t ws_size,
                              hipStream_t stream) {
    const float* noise = (const float*)d_in[0];
    const float* W_ih0 = (const float*)d_in[1];
    const float* W_hh0 = (const float*)d_in[2];
    const float* b_ih0 = (const float*)d_in[3];
    const float* b_hh0 = (const float*)d_in[4];
    const float* W_ih  = (const float*)d_in[5];
    const float* W_hh  = (const float*)d_in[6];
    const float* b_ih  = (const float*)d_in[7];
    const float* b_hh  = (const float*)d_in[8];

    // clear counters + rings each call (replay-safe)
    const size_t clear_bytes = RING_OFF_B + (size_t)10 * RING_PER_L * sizeof(u64);
    hipMemsetAsync(d_ws, 0, clear_bytes, stream);

    unsigned* cnt = (unsigned*)d_ws;
    u64* ring = (u64*)((char*)d_ws + RING_OFF_B);

    lstm_wave<<<dim3(NLAYER * RGN), dim3(NTHR), 0, stream>>>(
        noise, (float*)d_out, cnt, ring,
        W_ih0, W_hh0, b_ih0, b_hh0, W_ih, W_hh, b_ih, b_hh);
}